// Round 1
// baseline (232.432 us; speedup 1.0000x reference)
//
#include <hip/hip_runtime.h>

#define B_    4
#define CIN_  64
#define COUT_ 64
#define N_    16384
#define K_    8

// ---------------------------------------------------------------------------
// Main kernel: per (b, n-tile) compute ft[3][o], fb[o] for each point, then
// scatter contrib into transposed workspace ws[b][j][o] via atomics.
// Block = 256 threads (4 waves). Each block handles 2 tiles of 64 points.
// lane (= tid & 63) owns output channel o.
// ---------------------------------------------------------------------------
__global__ __launch_bounds__(256) void flexconv_main(
    const float* __restrict__ feat,    // [B, CIN, N]
    const float* __restrict__ theta,   // [3, CIN, COUT]
    const float* __restrict__ wbias,   // [CIN, COUT]
    const int*   __restrict__ nbh,     // [B, K, N]
    const float* __restrict__ pos,     // [B, 3, N]
    float*       __restrict__ ws)      // [B, N, COUT]  (transposed accumulator)
{
    __shared__ float4 Wl[CIN_ * COUT_];   // 64 KiB: (theta0,theta1,theta2,wb) per (i,o)
    __shared__ float  Fl[CIN_ * 64];      // 16 KiB feature tile [i][nn]

    const int tid  = threadIdx.x;
    const int lane = tid & 63;            // o
    const int w    = tid >> 6;            // wave id 0..3

    const int blocks_per_b = N_ / 128;    // 128
    const int b     = blockIdx.x / blocks_per_b;
    const int nbase = (blockIdx.x % blocks_per_b) * 128;

    // Stage interleaved weights into LDS (coalesced across o).
    for (int e = tid; e < CIN_ * COUT_; e += 256) {
        const int i = e >> 6, o = e & 63;
        float4 wv;
        wv.x = theta[0 * CIN_ * COUT_ + i * COUT_ + o];
        wv.y = theta[1 * CIN_ * COUT_ + i * COUT_ + o];
        wv.z = theta[2 * CIN_ * COUT_ + i * COUT_ + o];
        wv.w = wbias[i * COUT_ + o];
        Wl[e] = wv;
    }

    const float* featb = feat + (size_t)b * CIN_ * N_;
    const float* posb  = pos  + (size_t)b * 3 * N_;
    const int*   nbhb  = nbh  + (size_t)b * K_ * N_;
    float*       wsb   = ws   + (size_t)b * N_ * COUT_;

    for (int t = 0; t < 2; ++t) {
        const int n0 = nbase + t * 64;

        __syncthreads();   // Wl ready (t=0) / previous tile's Fl readers done (t=1)
        // Stage feature tile: row i, 64 consecutive n (coalesced).
        for (int r = 0; r < 16; ++r) {
            const int i = r * 4 + w;
            Fl[i * 64 + lane] = featb[(size_t)i * N_ + n0 + lane];
        }
        __syncthreads();

        // Each wave processes 16 points (4 groups of 4).
        for (int g = 0; g < 4; ++g) {
            const int nn = w * 16 + g * 4;
            float4 acc[4];
            #pragma unroll
            for (int j = 0; j < 4; ++j) acc[j] = make_float4(0.f, 0.f, 0.f, 0.f);

            #pragma unroll 8
            for (int i = 0; i < CIN_; ++i) {
                const float4 wv = Wl[i * 64 + lane];       // ds_read_b128, conflict-free
                const float f0 = Fl[i * 64 + nn + 0];      // broadcast
                const float f1 = Fl[i * 64 + nn + 1];
                const float f2 = Fl[i * 64 + nn + 2];
                const float f3 = Fl[i * 64 + nn + 3];
                acc[0].x = fmaf(wv.x, f0, acc[0].x);
                acc[0].y = fmaf(wv.y, f0, acc[0].y);
                acc[0].z = fmaf(wv.z, f0, acc[0].z);
                acc[0].w = fmaf(wv.w, f0, acc[0].w);
                acc[1].x = fmaf(wv.x, f1, acc[1].x);
                acc[1].y = fmaf(wv.y, f1, acc[1].y);
                acc[1].z = fmaf(wv.z, f1, acc[1].z);
                acc[1].w = fmaf(wv.w, f1, acc[1].w);
                acc[2].x = fmaf(wv.x, f2, acc[2].x);
                acc[2].y = fmaf(wv.y, f2, acc[2].y);
                acc[2].z = fmaf(wv.z, f2, acc[2].z);
                acc[2].w = fmaf(wv.w, f2, acc[2].w);
                acc[3].x = fmaf(wv.x, f3, acc[3].x);
                acc[3].y = fmaf(wv.y, f3, acc[3].y);
                acc[3].z = fmaf(wv.z, f3, acc[3].z);
                acc[3].w = fmaf(wv.w, f3, acc[3].w);
            }

            // Scatter: contrib[k,o] = delta . ft + fb  ->  ws[b][j][o]
            #pragma unroll
            for (int j = 0; j < 4; ++j) {
                const int n = n0 + nn + j;
                const float px = posb[0 * N_ + n];   // broadcast loads
                const float py = posb[1 * N_ + n];
                const float pz = posb[2 * N_ + n];
                const float4 a = acc[j];
                #pragma unroll
                for (int k = 0; k < K_; ++k) {
                    const int idx = nbhb[k * N_ + n];
                    const float dx = posb[0 * N_ + idx] - px;
                    const float dy = posb[1 * N_ + idx] - py;
                    const float dz = posb[2 * N_ + idx] - pz;
                    const float c  = fmaf(dx, a.x, fmaf(dy, a.y, fmaf(dz, a.z, a.w)));
                    atomicAdd(&wsb[(size_t)idx * COUT_ + lane], c);
                }
            }
        }
    }
}

// ---------------------------------------------------------------------------
// Finish: out[b][o][n] = ws[b][n][o] + bias[o]   (LDS tile transpose)
// ---------------------------------------------------------------------------
__global__ __launch_bounds__(256) void flexconv_finish(
    const float* __restrict__ ws,
    const float* __restrict__ bias,
    float*       __restrict__ out)
{
    __shared__ float T[64][65];
    const int tid  = threadIdx.x;
    const int lane = tid & 63;
    const int w    = tid >> 6;

    const int tiles_per_b = N_ / 64;      // 256
    const int b  = blockIdx.x / tiles_per_b;
    const int n0 = (blockIdx.x % tiles_per_b) * 64;

    const float* wsb = ws + (size_t)b * N_ * COUT_;
    for (int r = 0; r < 16; ++r) {
        const int nn = r * 4 + w;
        T[nn][lane] = wsb[(size_t)(n0 + nn) * COUT_ + lane];  // coalesced
    }
    __syncthreads();

    float* outb = out + (size_t)b * COUT_ * N_;
    for (int r = 0; r < 16; ++r) {
        const int o = r * 4 + w;
        outb[(size_t)o * N_ + n0 + lane] = T[lane][o] + bias[o];  // coalesced
    }
}

extern "C" void kernel_launch(void* const* d_in, const int* in_sizes, int n_in,
                              void* d_out, int out_size, void* d_ws, size_t ws_size,
                              hipStream_t stream) {
    const float* features = (const float*)d_in[0];
    const float* theta    = (const float*)d_in[1];
    const float* wbias    = (const float*)d_in[2];
    const int*   nbh      = (const int*)  d_in[3];
    const float* pos      = (const float*)d_in[4];
    const float* bias     = (const float*)d_in[5];
    float* out = (float*)d_out;
    float* ws  = (float*)d_ws;

    const size_t ws_bytes = (size_t)B_ * N_ * COUT_ * sizeof(float);  // 16 MiB
    hipMemsetAsync(ws, 0, ws_bytes, stream);

    flexconv_main<<<B_ * (N_ / 128), 256, 0, stream>>>(features, theta, wbias, nbh, pos, ws);
    flexconv_finish<<<B_ * (N_ / 64), 256, 0, stream>>>(ws, bias, out);
}